// Round 7
// baseline (157.670 us; speedup 1.0000x reference)
//
#include <hip/hip_runtime.h>
#include <stdint.h>

// MeshPoolFace: batched segment-mean pooling.
// fe: [B=16, C=256, F=16000] f32, gid: [B, F] int32 in [0, T=8000)
// out[b][c][t] = mean over {f : gid[b][f]==t} of fe[b][c][f]
//
// Round-14: scan_rank rewrite — zero LDS atomics. Round-11 measured LDS
// atomics at ~3 cyc/lane; scan_rank's two 8000-op contended LDS-atomic
// passes (hist2 count + cur2 rank) ~= 20us on just 16 CUs. Replaced with
// ballot-based ranking: per-wave register histograms (lane l owns bucket l,
// sizes clamped to 63 for BUCKETING only), shfl exclusive scan for bucket
// bases, rank = shfl(base, s) + popcount(ballot & below). Pool (113.5us
// champion config) unchanged: pair-packed sort-gather pipeline, uniform
// vmem counts, plain loads / NT stores, ds_read2 paired gather.

#define NB 16
#define NC 256
#define NF 16000
#define NT 8000
#define CPB 16  // channels per pool block (8 pairs); grid = NB*NC/CPB = 256

typedef unsigned int uint;
typedef unsigned short ushort;
typedef unsigned long long ull;
typedef float f32x4 __attribute__((ext_vector_type(4)));

__device__ __forceinline__ float bf2f(uint h) { return __uint_as_float(h << 16); }
__device__ __forceinline__ uint cvtpk(float lo, float hi) {
    uint r;
    asm("v_cvt_pk_bf16_f32 %0, %1, %2" : "=v"(r) : "v"(lo), "v"(hi));
    return r;
}

// K1: global histogram of group sizes. grid = 250.
__global__ __launch_bounds__(256) void hist_kernel(const int* __restrict__ gid,
                                                   int* __restrict__ cnt) {
    int i = blockIdx.x * 256 + threadIdx.x;
    if (i >= NB * NF / 4) return;
    int4 g = ((const int4*)gid)[i];
    int* c = cnt + (i / (NF / 4)) * NT;
    atomicAdd(&c[g.x], 1);
    atomicAdd(&c[g.y], 1);
    atomicAdd(&c[g.z], 1);
    atomicAdd(&c[g.w], 1);
}

// K2: per batch (grid=NB, 256 thr): exclusive scan of cnt -> off; size-
// bucketed rank order via BALLOT arithmetic (no LDS atomics):
//   gorder (rank->t), pk (rank -> off | n<<14), cursor = off copy.
__global__ __launch_bounds__(256) void scan_rank_kernel(const int* __restrict__ cnt_g,
                                                        uint* __restrict__ pk,
                                                        uint* __restrict__ cursor,
                                                        ushort* __restrict__ gorder) {
    __shared__ int off_s[NT];        // 32000 B
    __shared__ ushort nsz[NT];       // 16000 B: true group size (u16)
    __shared__ int partial[256];
    __shared__ int hh[4][64];        // per-wave bucket hist
    __shared__ int wbase[4][64];     // per-wave bucket base
    const int b = blockIdx.x, tid = threadIdx.x;
    const int w = tid >> 6, l = tid & 63;
    const int* cnt = cnt_g + b * NT;

    // phase 1: per-thread serial scan of 32 counts -> block exclusive scan
    int loc[32];
    int ts = 0;
    if (tid < 250) {
        const int4* c4 = (const int4*)(cnt + 32 * tid);
#pragma unroll
        for (int j = 0; j < 8; ++j) {
            int4 v = c4[j];
            loc[4 * j + 0] = ts; ts += v.x;
            loc[4 * j + 1] = ts; ts += v.y;
            loc[4 * j + 2] = ts; ts += v.z;
            loc[4 * j + 3] = ts; ts += v.w;
            nsz[32 * tid + 4 * j + 0] = (ushort)v.x;
            nsz[32 * tid + 4 * j + 1] = (ushort)v.y;
            nsz[32 * tid + 4 * j + 2] = (ushort)v.z;
            nsz[32 * tid + 4 * j + 3] = (ushort)v.w;
        }
    }
    partial[tid] = (tid < 250) ? ts : 0;
    __syncthreads();

    if (tid < 64) {
        int s0 = partial[4 * tid], s1 = partial[4 * tid + 1];
        int s2 = partial[4 * tid + 2], s3 = partial[4 * tid + 3];
        int lsum = s0 + s1 + s2 + s3;
        int inc = lsum;
        for (int d = 1; d < 64; d <<= 1) {
            int u = __shfl_up(inc, d);
            if (tid >= d) inc += u;
        }
        int exc = inc - lsum;
        partial[4 * tid + 0] = exc;
        partial[4 * tid + 1] = exc + s0;
        partial[4 * tid + 2] = exc + s0 + s1;
        partial[4 * tid + 3] = exc + s0 + s1 + s2;
    }
    __syncthreads();

    if (tid < 250) {
        int base = partial[tid];
#pragma unroll
        for (int j = 0; j < 32; ++j) off_s[32 * tid + j] = base + loc[j];
    }
    __syncthreads();

    // Phase A: per-wave bucket histogram via ballot; lane l accumulates
    // bucket l in a register. Item mapping (identical in phase B):
    // chunk j (j<32): t = 256*j + 64*w + l, valid if t < NT.
    int hacc = 0;
    for (int j = 0; j < 32; ++j) {
        int t = 256 * j + 64 * w + l;
        bool valid = t < NT;
        int n = valid ? (int)nsz[t] : -1;
        int s = (n > 63) ? 63 : n;          // -1 for invalid lanes
        int wm = s;
        for (int d = 1; d < 64; d <<= 1) wm = max(wm, __shfl_xor(wm, d));
        for (int ss = 0; ss <= wm; ++ss) {
            ull m = __ballot(s == ss);
            if (l == ss) hacc += (int)__popcll(m);
        }
    }
    hh[w][l] = hacc;
    __syncthreads();

    // Merge: bucket totals -> exclusive scan -> per-wave bases (wave 0).
    if (tid < 64) {
        int h0 = hh[0][l], h1 = hh[1][l], h2 = hh[2][l], h3 = hh[3][l];
        int tot = h0 + h1 + h2 + h3;
        int inc = tot;
        for (int d = 1; d < 64; d <<= 1) {
            int u = __shfl_up(inc, d);
            if (l >= d) inc += u;
        }
        int bb = inc - tot;                 // exclusive bucket base
        wbase[0][l] = bb;
        wbase[1][l] = bb + h0;
        wbase[2][l] = bb + h0 + h1;
        wbase[3][l] = bb + h0 + h1 + h2;
    }
    __syncthreads();

    // Phase B: assign ranks; write gorder/pk/cursor.
    uint* pkb = pk + (size_t)b * NT;
    uint* cb = cursor + (size_t)b * NT;
    ushort* gb = gorder + (size_t)b * NT;
    int rb = wbase[w][l];                   // lane l: running base, bucket l
    for (int j = 0; j < 32; ++j) {
        int t = 256 * j + 64 * w + l;
        bool valid = t < NT;
        int n = valid ? (int)nsz[t] : -1;
        int s = (n > 63) ? 63 : n;
        int wm = s;
        for (int d = 1; d < 64; d <<= 1) wm = max(wm, __shfl_xor(wm, d));
        int rnk = -1;
        for (int ss = 0; ss <= wm; ++ss) {
            ull m = __ballot(s == ss);
            if (m) {
                int base = __shfl(rb, ss);
                if (s == ss)
                    rnk = base + (int)__popcll(m & ((1ull << l) - 1ull));
                if (l == ss) rb += (int)__popcll(m);
            }
        }
        if (valid) {
            int o = off_s[t];
            gb[rnk] = (ushort)t;
            pkb[rnk] = (uint)o | ((uint)n << 14);   // off < 16384, n < 2^18
            cb[t] = (uint)o;
        }
    }
}

// K3: INVERSE permutation sp[b][f] = sorted position of face f.
// grid = NB*16 (atomic-latency-bound).
__global__ __launch_bounds__(256) void invperm_kernel(const int* __restrict__ gid,
                                                      uint* __restrict__ cursor,
                                                      ushort* __restrict__ sp) {
    const int b = blockIdx.x >> 4, q = blockIdx.x & 15;
    const int tid = threadIdx.x;
    if (tid >= 250) return;
    const int4* g4 = (const int4*)(gid + (size_t)b * NF + q * 1000);
    uint* cb = cursor + (size_t)b * NT;
    uint2* sp2 = (uint2*)(sp + (size_t)b * NF + q * 1000);  // 8B aligned
    int4 g = g4[tid];
    uint p0 = atomicAdd(&cb[g.x], 1u);
    uint p1 = atomicAdd(&cb[g.y], 1u);
    uint p2 = atomicAdd(&cb[g.z], 1u);
    uint p3 = atomicAdd(&cb[g.w], 1u);
    sp2[tid] = make_uint2(p0 | (p1 << 16), p2 | (p3 << 16));
}

// Raw barrier: drain own LDS ops, workgroup barrier. Never drains vmcnt,
// so global prefetch loads / NT stores stay in flight across it.
#define LGKM_BAR() do {                                          \
        asm volatile("s_waitcnt lgkmcnt(0)" ::: "memory");       \
        __builtin_amdgcn_s_barrier();                            \
        __builtin_amdgcn_sched_barrier(0);                       \
    } while (0)

// K4: pair-packed pool. grid = 256, 1024 thr, 128000 B dynamic LDS.
__global__ __launch_bounds__(1024) void pool_kernel(const float* __restrict__ fe,
                                                    const ushort* __restrict__ sp,
                                                    const uint* __restrict__ pk,
                                                    const ushort* __restrict__ gorder,
                                                    float* __restrict__ out) {
    extern __shared__ char smem[];
    uint* fes32 = (uint*)smem;                    // 64000 B: packed 2ch bf16
    float* outs = (float*)(smem + 64000);         // 64000 B: 2ch means
    const int bid = blockIdx.x;
    const int b = bid >> 4, cg = bid & 15;
    const int tid = threadIdx.x;
    const size_t bc0 = (size_t)(b * NC + cg * CPB);
    const bool t3 = (tid < 928);     // face tail: 4000 f32x4 per channel
    const bool tc = (tid < 976);     // out tail: 2000 f32x4 per channel
    const bool t8 = (tid < 832);     // rank tail: 8000 ranks
    const int tl = t3 ? tid + 3072 : tid;   // uniform-load index (dummy=tid)
    const int fi = tc ? tid + 1024 : 0;     // uniform-store index (dummy=0)

    // Register-cache inverse permutation (slot indices, packed u16 pairs)
    const uint2* sp2 = (const uint2*)(sp + (size_t)b * NF);
    uint2 s0 = sp2[tid];
    uint2 s1 = sp2[tid + 1024];
    uint2 s2 = sp2[tid + 2048];
    uint2 s3 = sp2[tl];   // garbage for !t3, never written

    // Register-cache pk/gorder (ranks {tid+it*1024, it<7} + {7168+tid,<832})
    const uint* pkb = pk + (size_t)b * NT;
    const ushort* gob = gorder + (size_t)b * NT;
    uint pv[8];
    ushort gv[8];
#pragma unroll
    for (int it = 0; it < 7; ++it) {
        pv[it] = pkb[tid + it * 1024];
        gv[it] = gob[tid + it * 1024];
    }
    pv[7] = 0; gv[7] = 0;
    if (t8) { pv[7] = pkb[7168 + tid]; gv[7] = gob[7168 + tid]; }

    const f32x4* fe4base = (const f32x4*)(fe + bc0 * NF);
    f32x4 a0, a1, a2, a3, b0, b1, b2, b3;

    // prologue: issue pair-0 loads (channels 0,1) — plain loads (L3 hits)
    {
        const f32x4* fA = fe4base;
        const f32x4* fB = fe4base + (NF / 4);
        a0 = fA[tid]; a1 = fA[tid + 1024]; a2 = fA[tid + 2048]; a3 = fA[tl];
        b0 = fB[tid]; b1 = fB[tid + 1024]; b2 = fB[tid + 2048]; b3 = fB[tl];
    }

#define PAIR_WRITE(S, VA, VB) do {                                       \
        fes32[(S).x & 0xFFFFu] = cvtpk((VA)[0], (VB)[0]);                \
        fes32[(S).x >> 16]     = cvtpk((VA)[1], (VB)[1]);                \
        fes32[(S).y & 0xFFFFu] = cvtpk((VA)[2], (VB)[2]);                \
        fes32[(S).y >> 16]     = cvtpk((VA)[3], (VB)[3]);                \
    } while (0)

// Paired gather: 8B LDS read (ds_read2_b32) = 2 members x 2 channels.
#define GATHER(P, GVI) do {                                              \
        uint p_ = (P);                                                   \
        uint off_ = p_ & 0x3FFFu, n_ = p_ >> 14;                         \
        float sa_ = 0.f, sb_ = 0.f;                                      \
        uint r_ = 0;                                                     \
        for (; r_ + 2 <= n_; r_ += 2) {                                  \
            uint2 w_;                                                    \
            __builtin_memcpy(&w_, &fes32[off_ + r_], 8);                 \
            sa_ += bf2f(w_.x & 0xFFFFu) + bf2f(w_.y & 0xFFFFu);          \
            sb_ += bf2f(w_.x >> 16) + bf2f(w_.y >> 16);                  \
        }                                                                \
        if (r_ < n_) {                                                   \
            uint w_ = fes32[off_ + r_];                                  \
            sa_ += bf2f(w_ & 0xFFFFu);                                   \
            sb_ += bf2f(w_ >> 16);                                       \
        }                                                                \
        float rn_ = n_ ? __builtin_amdgcn_rcpf((float)n_) : 0.f;         \
        outs[GVI] = sa_ * rn_;                                           \
        outs[NT + GVI] = sb_ * rn_;                                      \
    } while (0)

#pragma unroll
    for (int k = 0; k < CPB / 2; ++k) {
        // WRITE: consume current pair regs (progressive vmcnt waits)
        PAIR_WRITE(s0, a0, b0);
        PAIR_WRITE(s1, a1, b1);
        PAIR_WRITE(s2, a2, b2);
        if (t3) PAIR_WRITE(s3, a3, b3);

        // prefetch next pair: uniform 8 loads, in flight across the window
        if (k + 1 < CPB / 2) {
            const f32x4* fA = fe4base + (size_t)(2 * k + 2) * (NF / 4);
            const f32x4* fB = fA + (NF / 4);
            a0 = fA[tid]; a1 = fA[tid + 1024]; a2 = fA[tid + 2048]; a3 = fA[tl];
            b0 = fB[tid]; b1 = fB[tid + 1024]; b2 = fB[tid + 2048]; b3 = fB[tl];
        }

        LGKM_BAR();   // fes32 ready

        // P1: gather both channels per rank; scatter means to outs.
#pragma unroll
        for (int it = 0; it < 7; ++it) GATHER(pv[it], gv[it]);
        if (t8) GATHER(pv[7], gv[7]);

        LGKM_BAR();   // outs ready; fes32 fully consumed

        // FLUSH: coalesced NT f32x4, both channels. Uniform 4 stores/thread
        // (tail threads re-store element 0 — identical bytes, idempotent).
        {
            const f32x4* oa = (const f32x4*)outs;
            const f32x4* ob = (const f32x4*)(outs + NT);
            f32x4* oA = (f32x4*)(out + (bc0 + (size_t)(2 * k)) * NT);
            f32x4* oB = (f32x4*)(out + (bc0 + (size_t)(2 * k + 1)) * NT);
            f32x4 vA0 = oa[tid], vA1 = oa[fi];
            f32x4 vB0 = ob[tid], vB1 = ob[fi];
            __builtin_nontemporal_store(vA0, &oA[tid]);
            __builtin_nontemporal_store(vA1, &oA[fi]);
            __builtin_nontemporal_store(vB0, &oB[tid]);
            __builtin_nontemporal_store(vB1, &oB[fi]);
        }
    }
#undef GATHER
#undef PAIR_WRITE
}

// Fallback (round-2 path) if workspace is too small.
__device__ __forceinline__ void lds_fadd(unsigned addr, float v) {
    asm volatile("ds_add_f32 %0, %1" :: "v"(addr), "v"(v));
}
__global__ __launch_bounds__(256) void pool_fused_kernel(const float* __restrict__ fe,
                                                         const int* __restrict__ gid,
                                                         float* __restrict__ out) {
    __shared__ float acc[NT];
    __shared__ int cnt[NT];
    const int bc = blockIdx.x, b = bc >> 8, tid = threadIdx.x;
    for (int t = tid; t < NT; t += 256) { acc[t] = 0.0f; cnt[t] = 0; }
    __syncthreads();
    const unsigned accb = (unsigned)(uintptr_t)acc;
    const float4* fe4 = (const float4*)(fe + (size_t)bc * NF);
    const int4* gid4 = (const int4*)(gid + (size_t)b * NF);
    for (int i = tid; i < NF / 4; i += 256) {
        float4 v = fe4[i];
        int4 g = gid4[i];
        lds_fadd(accb + 4u * (unsigned)g.x, v.x); atomicAdd(&cnt[g.x], 1);
        lds_fadd(accb + 4u * (unsigned)g.y, v.y); atomicAdd(&cnt[g.y], 1);
        lds_fadd(accb + 4u * (unsigned)g.z, v.z); atomicAdd(&cnt[g.z], 1);
        lds_fadd(accb + 4u * (unsigned)g.w, v.w); atomicAdd(&cnt[g.w], 1);
    }
    asm volatile("s_waitcnt lgkmcnt(0)" ::: "memory");
    __syncthreads();
    float* orow = out + (size_t)bc * NT;
    for (int t = tid; t < NT; t += 256) {
        int n = cnt[t];
        orow[t] = acc[t] / (float)(n > 0 ? n : 1);
    }
}

extern "C" void kernel_launch(void* const* d_in, const int* in_sizes, int n_in,
                              void* d_out, int out_size, void* d_ws, size_t ws_size,
                              hipStream_t stream) {
    const float* fe = (const float*)d_in[0];
    const int* gid = (const int*)d_in[1];
    float* out = (float*)d_out;

    // workspace layout (bytes)
    const size_t O_CNT = 0;          // int [NB*NT]   512000
    const size_t O_CUR = 512000;     // u32 [NB*NT]   512000
    const size_t O_PK  = 1024000;    // u32 [NB*NT]   512000
    const size_t O_GO  = 1536000;    // u16 [NB*NT]   256000
    const size_t O_SP  = 1792000;    // u16 [NB*NF]   512000
    const size_t TOTAL = 2304000;

    if (ws_size >= TOTAL) {
        char* w = (char*)d_ws;
        int* cnt = (int*)(w + O_CNT);
        uint* cursor = (uint*)(w + O_CUR);
        uint* pk = (uint*)(w + O_PK);
        ushort* gorder = (ushort*)(w + O_GO);
        ushort* sp = (ushort*)(w + O_SP);

        static bool lds_opted = false;
        if (!lds_opted) {
            (void)hipFuncSetAttribute((const void*)pool_kernel,
                                      hipFuncAttributeMaxDynamicSharedMemorySize,
                                      128000);
            lds_opted = true;
        }

        (void)hipMemsetAsync(cnt, 0, 512000, stream);
        hist_kernel<<<(NB * NF / 4 + 255) / 256, 256, 0, stream>>>(gid, cnt);
        scan_rank_kernel<<<NB, 256, 0, stream>>>(cnt, pk, cursor, gorder);
        invperm_kernel<<<NB * 16, 256, 0, stream>>>(gid, cursor, sp);
        pool_kernel<<<NB * (NC / CPB), 1024, 128000, stream>>>(fe, sp, pk, gorder, out);
    } else {
        pool_fused_kernel<<<NB * NC, 256, 0, stream>>>(fe, gid, out);
    }
}

// Round 8
// 109.676 us; speedup vs baseline: 1.4376x; 1.4376x over previous
//
#include <hip/hip_runtime.h>
#include <stdint.h>

// MeshPoolFace: batched segment-mean pooling.
// fe: [B=16, C=256, F=16000] f32, gid: [B, F] int32 in [0, T=8000)
// out[b][c][t] = mean over {f : gid[b][f]==t} of fe[b][c][f]
//
// Round-15: DELETE the size-sort. r14's ballot scan_rank regressed (+44us);
// r13 A/B triangulation puts scan_rank+invperm at ~26us, dominated by two
// contended 8000-op LDS-atomic passes whose only purpose was wave-uniform n
// in the pool gather. Unsorted divergence costs ~E[max of 64 Poisson(2)]=7
// iterations vs 2 -> ~+1.7us in pool. So: rank == t identity, gorder
// deleted, pk[t]=off|n<<14 written directly, scan_rank = pure scan (~3us).
// Slot assignment (cursor/invperm) unchanged -> bitwise-identical output.
// Pool = r13 champion config: pair-packed sort-gather pipeline, uniform
// vmem counts, plain loads / NT stores, ds_read2 paired gather, LGKM_BAR.

#define NB 16
#define NC 256
#define NF 16000
#define NT 8000
#define CPB 16  // channels per pool block (8 pairs); grid = NB*NC/CPB = 256

typedef unsigned int uint;
typedef unsigned short ushort;
typedef float f32x4 __attribute__((ext_vector_type(4)));

__device__ __forceinline__ float bf2f(uint h) { return __uint_as_float(h << 16); }
__device__ __forceinline__ uint cvtpk(float lo, float hi) {
    uint r;
    asm("v_cvt_pk_bf16_f32 %0, %1, %2" : "=v"(r) : "v"(lo), "v"(hi));
    return r;
}

// K1: global histogram of group sizes. grid = 250.
__global__ __launch_bounds__(256) void hist_kernel(const int* __restrict__ gid,
                                                   int* __restrict__ cnt) {
    int i = blockIdx.x * 256 + threadIdx.x;
    if (i >= NB * NF / 4) return;
    int4 g = ((const int4*)gid)[i];
    int* c = cnt + (i / (NF / 4)) * NT;
    atomicAdd(&c[g.x], 1);
    atomicAdd(&c[g.y], 1);
    atomicAdd(&c[g.z], 1);
    atomicAdd(&c[g.w], 1);
}

// K2: per batch (grid=NB): exclusive scan of cnt -> off; write
// pk[t] = off | n<<14 and cursor[t] = off. No ranking, no atomics.
__global__ __launch_bounds__(256) void scan_kernel(const int* __restrict__ cnt_g,
                                                   uint* __restrict__ pk,
                                                   uint* __restrict__ cursor) {
    __shared__ int partial[256];
    const int b = blockIdx.x, tid = threadIdx.x;
    const int* cnt = cnt_g + b * NT;

    int loc[32], nv[32];
    int ts = 0;
    if (tid < 250) {
        const int4* c4 = (const int4*)(cnt + 32 * tid);
#pragma unroll
        for (int j = 0; j < 8; ++j) {
            int4 v = c4[j];
            loc[4 * j + 0] = ts; nv[4 * j + 0] = v.x; ts += v.x;
            loc[4 * j + 1] = ts; nv[4 * j + 1] = v.y; ts += v.y;
            loc[4 * j + 2] = ts; nv[4 * j + 2] = v.z; ts += v.z;
            loc[4 * j + 3] = ts; nv[4 * j + 3] = v.w; ts += v.w;
        }
    }
    partial[tid] = (tid < 250) ? ts : 0;
    __syncthreads();

    if (tid < 64) {
        int s0 = partial[4 * tid], s1 = partial[4 * tid + 1];
        int s2 = partial[4 * tid + 2], s3 = partial[4 * tid + 3];
        int lsum = s0 + s1 + s2 + s3;
        int inc = lsum;
        for (int d = 1; d < 64; d <<= 1) {
            int u = __shfl_up(inc, d);
            if (tid >= d) inc += u;
        }
        int exc = inc - lsum;
        partial[4 * tid + 0] = exc;
        partial[4 * tid + 1] = exc + s0;
        partial[4 * tid + 2] = exc + s0 + s1;
        partial[4 * tid + 3] = exc + s0 + s1 + s2;
    }
    __syncthreads();

    if (tid < 250) {
        int base = partial[tid];
        uint* pkb = pk + (size_t)b * NT + 32 * tid;
        uint* cb = cursor + (size_t)b * NT + 32 * tid;
#pragma unroll
        for (int j = 0; j < 32; ++j) {
            uint o = (uint)(base + loc[j]);
            pkb[j] = o | ((uint)nv[j] << 14);   // off < 16384, n < 2^18
            cb[j] = o;
        }
    }
}

// K3: INVERSE permutation sp[b][f] = slot of face f (off[g] + occurrence).
// grid = NB*16 (atomic-latency-bound).
__global__ __launch_bounds__(256) void invperm_kernel(const int* __restrict__ gid,
                                                      uint* __restrict__ cursor,
                                                      ushort* __restrict__ sp) {
    const int b = blockIdx.x >> 4, q = blockIdx.x & 15;
    const int tid = threadIdx.x;
    if (tid >= 250) return;
    const int4* g4 = (const int4*)(gid + (size_t)b * NF + q * 1000);
    uint* cb = cursor + (size_t)b * NT;
    uint2* sp2 = (uint2*)(sp + (size_t)b * NF + q * 1000);  // 8B aligned
    int4 g = g4[tid];
    uint p0 = atomicAdd(&cb[g.x], 1u);
    uint p1 = atomicAdd(&cb[g.y], 1u);
    uint p2 = atomicAdd(&cb[g.z], 1u);
    uint p3 = atomicAdd(&cb[g.w], 1u);
    sp2[tid] = make_uint2(p0 | (p1 << 16), p2 | (p3 << 16));
}

// Raw barrier: drain own LDS ops, workgroup barrier. Never drains vmcnt,
// so global prefetch loads / NT stores stay in flight across it.
#define LGKM_BAR() do {                                          \
        asm volatile("s_waitcnt lgkmcnt(0)" ::: "memory");       \
        __builtin_amdgcn_s_barrier();                            \
        __builtin_amdgcn_sched_barrier(0);                       \
    } while (0)

// K4: pair-packed pool. grid = 256, 1024 thr, 128000 B dynamic LDS.
__global__ __launch_bounds__(1024) void pool_kernel(const float* __restrict__ fe,
                                                    const ushort* __restrict__ sp,
                                                    const uint* __restrict__ pk,
                                                    float* __restrict__ out) {
    extern __shared__ char smem[];
    uint* fes32 = (uint*)smem;                    // 64000 B: packed 2ch bf16
    float* outs = (float*)(smem + 64000);         // 64000 B: 2ch means
    const int bid = blockIdx.x;
    const int b = bid >> 4, cg = bid & 15;
    const int tid = threadIdx.x;
    const size_t bc0 = (size_t)(b * NC + cg * CPB);
    const bool t3 = (tid < 928);     // face tail: 4000 f32x4 per channel
    const bool tc = (tid < 976);     // out tail: 2000 f32x4 per channel
    const bool t8 = (tid < 832);     // group tail: 8000 groups
    const int tl = t3 ? tid + 3072 : tid;   // uniform-load index (dummy=tid)
    const int fi = tc ? tid + 1024 : 0;     // uniform-store index (dummy=0)

    // Register-cache inverse permutation (slot indices, packed u16 pairs)
    const uint2* sp2 = (const uint2*)(sp + (size_t)b * NF);
    uint2 s0 = sp2[tid];
    uint2 s1 = sp2[tid + 1024];
    uint2 s2 = sp2[tid + 2048];
    uint2 s3 = sp2[tl];   // garbage for !t3, never written

    // Register-cache pk (groups t = {tid+it*1024, it<7} + {7168+tid,<832});
    // rank == t identity, so the outs index is computable — no gorder.
    const uint* pkb = pk + (size_t)b * NT;
    uint pv[8];
#pragma unroll
    for (int it = 0; it < 7; ++it) pv[it] = pkb[tid + it * 1024];
    pv[7] = 0;
    if (t8) pv[7] = pkb[7168 + tid];

    const f32x4* fe4base = (const f32x4*)(fe + bc0 * NF);
    f32x4 a0, a1, a2, a3, b0, b1, b2, b3;

    // prologue: issue pair-0 loads (channels 0,1) — plain loads (L3 hits)
    {
        const f32x4* fA = fe4base;
        const f32x4* fB = fe4base + (NF / 4);
        a0 = fA[tid]; a1 = fA[tid + 1024]; a2 = fA[tid + 2048]; a3 = fA[tl];
        b0 = fB[tid]; b1 = fB[tid + 1024]; b2 = fB[tid + 2048]; b3 = fB[tl];
    }

#define PAIR_WRITE(S, VA, VB) do {                                       \
        fes32[(S).x & 0xFFFFu] = cvtpk((VA)[0], (VB)[0]);                \
        fes32[(S).x >> 16]     = cvtpk((VA)[1], (VB)[1]);                \
        fes32[(S).y & 0xFFFFu] = cvtpk((VA)[2], (VB)[2]);                \
        fes32[(S).y >> 16]     = cvtpk((VA)[3], (VB)[3]);                \
    } while (0)

// Paired gather: 8B LDS read (ds_read2_b32) = 2 members x 2 channels.
// n is per-lane (unsorted); wave runs to wave-max n (~7), cheap.
#define GATHER(P, GVI) do {                                              \
        uint p_ = (P);                                                   \
        uint off_ = p_ & 0x3FFFu, n_ = p_ >> 14;                         \
        float sa_ = 0.f, sb_ = 0.f;                                      \
        uint r_ = 0;                                                     \
        for (; r_ + 2 <= n_; r_ += 2) {                                  \
            uint2 w_;                                                    \
            __builtin_memcpy(&w_, &fes32[off_ + r_], 8);                 \
            sa_ += bf2f(w_.x & 0xFFFFu) + bf2f(w_.y & 0xFFFFu);          \
            sb_ += bf2f(w_.x >> 16) + bf2f(w_.y >> 16);                  \
        }                                                                \
        if (r_ < n_) {                                                   \
            uint w_ = fes32[off_ + r_];                                  \
            sa_ += bf2f(w_ & 0xFFFFu);                                   \
            sb_ += bf2f(w_ >> 16);                                       \
        }                                                                \
        float rn_ = n_ ? __builtin_amdgcn_rcpf((float)n_) : 0.f;         \
        outs[GVI] = sa_ * rn_;                                           \
        outs[NT + GVI] = sb_ * rn_;                                      \
    } while (0)

#pragma unroll
    for (int k = 0; k < CPB / 2; ++k) {
        // WRITE: consume current pair regs (progressive vmcnt waits)
        PAIR_WRITE(s0, a0, b0);
        PAIR_WRITE(s1, a1, b1);
        PAIR_WRITE(s2, a2, b2);
        if (t3) PAIR_WRITE(s3, a3, b3);

        // prefetch next pair: uniform 8 loads, in flight across the window
        if (k + 1 < CPB / 2) {
            const f32x4* fA = fe4base + (size_t)(2 * k + 2) * (NF / 4);
            const f32x4* fB = fA + (NF / 4);
            a0 = fA[tid]; a1 = fA[tid + 1024]; a2 = fA[tid + 2048]; a3 = fA[tl];
            b0 = fB[tid]; b1 = fB[tid + 1024]; b2 = fB[tid + 2048]; b3 = fB[tl];
        }

        LGKM_BAR();   // fes32 ready

        // P1: gather both channels per group; means to outs at index t.
#pragma unroll
        for (int it = 0; it < 7; ++it) GATHER(pv[it], tid + it * 1024);
        if (t8) GATHER(pv[7], 7168 + tid);

        LGKM_BAR();   // outs ready; fes32 fully consumed

        // FLUSH: coalesced NT f32x4, both channels. Uniform 4 stores/thread
        // (tail threads re-store element 0 — identical bytes, idempotent).
        {
            const f32x4* oa = (const f32x4*)outs;
            const f32x4* ob = (const f32x4*)(outs + NT);
            f32x4* oA = (f32x4*)(out + (bc0 + (size_t)(2 * k)) * NT);
            f32x4* oB = (f32x4*)(out + (bc0 + (size_t)(2 * k + 1)) * NT);
            f32x4 vA0 = oa[tid], vA1 = oa[fi];
            f32x4 vB0 = ob[tid], vB1 = ob[fi];
            __builtin_nontemporal_store(vA0, &oA[tid]);
            __builtin_nontemporal_store(vA1, &oA[fi]);
            __builtin_nontemporal_store(vB0, &oB[tid]);
            __builtin_nontemporal_store(vB1, &oB[fi]);
        }
    }
#undef GATHER
#undef PAIR_WRITE
}

// Fallback (round-2 path) if workspace is too small.
__device__ __forceinline__ void lds_fadd(unsigned addr, float v) {
    asm volatile("ds_add_f32 %0, %1" :: "v"(addr), "v"(v));
}
__global__ __launch_bounds__(256) void pool_fused_kernel(const float* __restrict__ fe,
                                                         const int* __restrict__ gid,
                                                         float* __restrict__ out) {
    __shared__ float acc[NT];
    __shared__ int cnt[NT];
    const int bc = blockIdx.x, b = bc >> 8, tid = threadIdx.x;
    for (int t = tid; t < NT; t += 256) { acc[t] = 0.0f; cnt[t] = 0; }
    __syncthreads();
    const unsigned accb = (unsigned)(uintptr_t)acc;
    const float4* fe4 = (const float4*)(fe + (size_t)bc * NF);
    const int4* gid4 = (const int4*)(gid + (size_t)b * NF);
    for (int i = tid; i < NF / 4; i += 256) {
        float4 v = fe4[i];
        int4 g = gid4[i];
        lds_fadd(accb + 4u * (unsigned)g.x, v.x); atomicAdd(&cnt[g.x], 1);
        lds_fadd(accb + 4u * (unsigned)g.y, v.y); atomicAdd(&cnt[g.y], 1);
        lds_fadd(accb + 4u * (unsigned)g.z, v.z); atomicAdd(&cnt[g.z], 1);
        lds_fadd(accb + 4u * (unsigned)g.w, v.w); atomicAdd(&cnt[g.w], 1);
    }
    asm volatile("s_waitcnt lgkmcnt(0)" ::: "memory");
    __syncthreads();
    float* orow = out + (size_t)bc * NT;
    for (int t = tid; t < NT; t += 256) {
        int n = cnt[t];
        orow[t] = acc[t] / (float)(n > 0 ? n : 1);
    }
}

extern "C" void kernel_launch(void* const* d_in, const int* in_sizes, int n_in,
                              void* d_out, int out_size, void* d_ws, size_t ws_size,
                              hipStream_t stream) {
    const float* fe = (const float*)d_in[0];
    const int* gid = (const int*)d_in[1];
    float* out = (float*)d_out;

    // workspace layout (bytes)
    const size_t O_CNT = 0;          // int [NB*NT]   512000
    const size_t O_CUR = 512000;     // u32 [NB*NT]   512000
    const size_t O_PK  = 1024000;    // u32 [NB*NT]   512000
    const size_t O_SP  = 1536000;    // u16 [NB*NF]   512000
    const size_t TOTAL = 2048000;

    if (ws_size >= TOTAL) {
        char* w = (char*)d_ws;
        int* cnt = (int*)(w + O_CNT);
        uint* cursor = (uint*)(w + O_CUR);
        uint* pk = (uint*)(w + O_PK);
        ushort* sp = (ushort*)(w + O_SP);

        static bool lds_opted = false;
        if (!lds_opted) {
            (void)hipFuncSetAttribute((const void*)pool_kernel,
                                      hipFuncAttributeMaxDynamicSharedMemorySize,
                                      128000);
            lds_opted = true;
        }

        (void)hipMemsetAsync(cnt, 0, 512000, stream);
        hist_kernel<<<(NB * NF / 4 + 255) / 256, 256, 0, stream>>>(gid, cnt);
        scan_kernel<<<NB, 256, 0, stream>>>(cnt, pk, cursor);
        invperm_kernel<<<NB * 16, 256, 0, stream>>>(gid, cursor, sp);
        pool_kernel<<<NB * (NC / CPB), 1024, 128000, stream>>>(fe, sp, pk, out);
    } else {
        pool_fused_kernel<<<NB * NC, 256, 0, stream>>>(fe, gid, out);
    }
}

// Round 9
// 106.581 us; speedup vs baseline: 1.4793x; 1.0290x over previous
//
#include <hip/hip_runtime.h>
#include <stdint.h>

// MeshPoolFace: batched segment-mean pooling.
// fe: [B=16, C=256, F=16000] f32, gid: [B, F] int32 in [0, T=8000)
// out[b][c][t] = mean over {f : gid[b][f]==t} of fe[b][c][f]
//
// Round-16: rank==t (r15) made the gather's output indices consecutive in
// tid -> the outs staging buffer is vestigial. Delete it: gather stores
// means DIRECTLY to out (coalesced NT dwords: wave = 256B contiguous, full
// lines -> no r8-style write amplification). Freed 64 KB double-buffers
// fes32 -> scatter(k+1) and gather(k) use different buffers -> ONE barrier
// per window. Per-window LDS ops -40%, barriers halved, flush deleted.
// Same slots/summation order -> bitwise-identical output vs r15.

#define NB 16
#define NC 256
#define NF 16000
#define NT 8000
#define CPB 16  // channels per pool block (8 pair-windows); grid = 256

typedef unsigned int uint;
typedef unsigned short ushort;
typedef float f32x4 __attribute__((ext_vector_type(4)));

__device__ __forceinline__ float bf2f(uint h) { return __uint_as_float(h << 16); }
__device__ __forceinline__ uint cvtpk(float lo, float hi) {
    uint r;
    asm("v_cvt_pk_bf16_f32 %0, %1, %2" : "=v"(r) : "v"(lo), "v"(hi));
    return r;
}

// K1: global histogram of group sizes. grid = 250.
__global__ __launch_bounds__(256) void hist_kernel(const int* __restrict__ gid,
                                                   int* __restrict__ cnt) {
    int i = blockIdx.x * 256 + threadIdx.x;
    if (i >= NB * NF / 4) return;
    int4 g = ((const int4*)gid)[i];
    int* c = cnt + (i / (NF / 4)) * NT;
    atomicAdd(&c[g.x], 1);
    atomicAdd(&c[g.y], 1);
    atomicAdd(&c[g.z], 1);
    atomicAdd(&c[g.w], 1);
}

// K2: per batch (grid=NB): exclusive scan of cnt -> off; write
// pk[t] = off | n<<14 and cursor[t] = off. No ranking, no atomics.
__global__ __launch_bounds__(256) void scan_kernel(const int* __restrict__ cnt_g,
                                                   uint* __restrict__ pk,
                                                   uint* __restrict__ cursor) {
    __shared__ int partial[256];
    const int b = blockIdx.x, tid = threadIdx.x;
    const int* cnt = cnt_g + b * NT;

    int loc[32], nv[32];
    int ts = 0;
    if (tid < 250) {
        const int4* c4 = (const int4*)(cnt + 32 * tid);
#pragma unroll
        for (int j = 0; j < 8; ++j) {
            int4 v = c4[j];
            loc[4 * j + 0] = ts; nv[4 * j + 0] = v.x; ts += v.x;
            loc[4 * j + 1] = ts; nv[4 * j + 1] = v.y; ts += v.y;
            loc[4 * j + 2] = ts; nv[4 * j + 2] = v.z; ts += v.z;
            loc[4 * j + 3] = ts; nv[4 * j + 3] = v.w; ts += v.w;
        }
    }
    partial[tid] = (tid < 250) ? ts : 0;
    __syncthreads();

    if (tid < 64) {
        int s0 = partial[4 * tid], s1 = partial[4 * tid + 1];
        int s2 = partial[4 * tid + 2], s3 = partial[4 * tid + 3];
        int lsum = s0 + s1 + s2 + s3;
        int inc = lsum;
        for (int d = 1; d < 64; d <<= 1) {
            int u = __shfl_up(inc, d);
            if (tid >= d) inc += u;
        }
        int exc = inc - lsum;
        partial[4 * tid + 0] = exc;
        partial[4 * tid + 1] = exc + s0;
        partial[4 * tid + 2] = exc + s0 + s1;
        partial[4 * tid + 3] = exc + s0 + s1 + s2;
    }
    __syncthreads();

    if (tid < 250) {
        int base = partial[tid];
        uint* pkb = pk + (size_t)b * NT + 32 * tid;
        uint* cb = cursor + (size_t)b * NT + 32 * tid;
#pragma unroll
        for (int j = 0; j < 32; ++j) {
            uint o = (uint)(base + loc[j]);
            pkb[j] = o | ((uint)nv[j] << 14);   // off < 16384, n < 2^18
            cb[j] = o;
        }
    }
}

// K3: INVERSE permutation sp[b][f] = slot of face f (off[g] + occurrence).
// grid = NB*16 (atomic-latency-bound).
__global__ __launch_bounds__(256) void invperm_kernel(const int* __restrict__ gid,
                                                      uint* __restrict__ cursor,
                                                      ushort* __restrict__ sp) {
    const int b = blockIdx.x >> 4, q = blockIdx.x & 15;
    const int tid = threadIdx.x;
    if (tid >= 250) return;
    const int4* g4 = (const int4*)(gid + (size_t)b * NF + q * 1000);
    uint* cb = cursor + (size_t)b * NT;
    uint2* sp2 = (uint2*)(sp + (size_t)b * NF + q * 1000);  // 8B aligned
    int4 g = g4[tid];
    uint p0 = atomicAdd(&cb[g.x], 1u);
    uint p1 = atomicAdd(&cb[g.y], 1u);
    uint p2 = atomicAdd(&cb[g.z], 1u);
    uint p3 = atomicAdd(&cb[g.w], 1u);
    sp2[tid] = make_uint2(p0 | (p1 << 16), p2 | (p3 << 16));
}

// Raw barrier: drain own LDS ops, workgroup barrier. Never drains vmcnt,
// so global prefetch loads / NT stores stay in flight across it.
#define LGKM_BAR() do {                                          \
        asm volatile("s_waitcnt lgkmcnt(0)" ::: "memory");       \
        __builtin_amdgcn_s_barrier();                            \
        __builtin_amdgcn_sched_barrier(0);                       \
    } while (0)

// K4: pair-packed pool, double-buffered fes32, direct coalesced store.
// grid = 256, 1024 thr, 128000 B dynamic LDS (2 x 64000 fes buffers).
// Per window: scatter pair k -> buf(k&1) / prefetch k+1 / LGKM_BAR /
// gather buf(k&1) + NT dword stores to out. One barrier per window.
__global__ __launch_bounds__(1024) void pool_kernel(const float* __restrict__ fe,
                                                    const ushort* __restrict__ sp,
                                                    const uint* __restrict__ pk,
                                                    float* __restrict__ out) {
    extern __shared__ char smem[];
    uint* fes32 = (uint*)smem;   // 2 x 16000 u32: packed 2ch bf16 per face
    const int bid = blockIdx.x;
    const int b = bid >> 4, cg = bid & 15;
    const int tid = threadIdx.x;
    const size_t bc0 = (size_t)(b * NC + cg * CPB);
    const bool t3 = (tid < 928);     // face tail: 4000 f32x4 per channel
    const bool t8 = (tid < 832);     // group tail: 8000 groups
    const int tl = t3 ? tid + 3072 : tid;   // uniform-load index (dummy=tid)

    // Register-cache inverse permutation (slot indices, packed u16 pairs)
    const uint2* sp2 = (const uint2*)(sp + (size_t)b * NF);
    uint2 s0 = sp2[tid];
    uint2 s1 = sp2[tid + 1024];
    uint2 s2 = sp2[tid + 2048];
    uint2 s3 = sp2[tl];   // garbage for !t3, never written

    // Register-cache pk (groups t = {tid+it*1024, it<7} + {7168+tid,<832})
    const uint* pkb = pk + (size_t)b * NT;
    uint pv[8];
#pragma unroll
    for (int it = 0; it < 7; ++it) pv[it] = pkb[tid + it * 1024];
    pv[7] = 0;
    if (t8) pv[7] = pkb[7168 + tid];

    const f32x4* fe4base = (const f32x4*)(fe + bc0 * NF);
    f32x4 a0, a1, a2, a3, b0, b1, b2, b3;

    // prologue: issue pair-0 loads (channels 0,1) — plain loads (L3 hits)
    {
        const f32x4* fA = fe4base;
        const f32x4* fB = fe4base + (NF / 4);
        a0 = fA[tid]; a1 = fA[tid + 1024]; a2 = fA[tid + 2048]; a3 = fA[tl];
        b0 = fB[tid]; b1 = fB[tid + 1024]; b2 = fB[tid + 2048]; b3 = fB[tl];
    }

#define PAIR_WRITE(F, S, VA, VB) do {                                    \
        (F)[(S).x & 0xFFFFu] = cvtpk((VA)[0], (VB)[0]);                  \
        (F)[(S).x >> 16]     = cvtpk((VA)[1], (VB)[1]);                  \
        (F)[(S).y & 0xFFFFu] = cvtpk((VA)[2], (VB)[2]);                  \
        (F)[(S).y >> 16]     = cvtpk((VA)[3], (VB)[3]);                  \
    } while (0)

// Paired gather + direct coalesced NT dword stores (consecutive t across
// consecutive threads -> wave stores 256B contiguous, full lines).
#define GATHER_ST(F, P, T) do {                                          \
        uint p_ = (P);                                                   \
        uint off_ = p_ & 0x3FFFu, n_ = p_ >> 14;                         \
        float sa_ = 0.f, sb_ = 0.f;                                      \
        uint r_ = 0;                                                     \
        for (; r_ + 2 <= n_; r_ += 2) {                                  \
            uint2 w_;                                                    \
            __builtin_memcpy(&w_, &(F)[off_ + r_], 8);                   \
            sa_ += bf2f(w_.x & 0xFFFFu) + bf2f(w_.y & 0xFFFFu);          \
            sb_ += bf2f(w_.x >> 16) + bf2f(w_.y >> 16);                  \
        }                                                                \
        if (r_ < n_) {                                                   \
            uint w_ = (F)[off_ + r_];                                    \
            sa_ += bf2f(w_ & 0xFFFFu);                                   \
            sb_ += bf2f(w_ >> 16);                                       \
        }                                                                \
        float rn_ = n_ ? __builtin_amdgcn_rcpf((float)n_) : 0.f;         \
        __builtin_nontemporal_store(sa_ * rn_, &oA[T]);                  \
        __builtin_nontemporal_store(sb_ * rn_, &oB[T]);                  \
    } while (0)

#pragma unroll
    for (int k = 0; k < CPB / 2; ++k) {
        uint* F = fes32 + (k & 1) * 16000;

        // scatter pair k into buf(k&1); gather(k-1) read buf((k-1)&1) — no
        // conflict; barrier at window k-1 ordered gather(k-2) before this.
        PAIR_WRITE(F, s0, a0, b0);
        PAIR_WRITE(F, s1, a1, b1);
        PAIR_WRITE(F, s2, a2, b2);
        if (t3) PAIR_WRITE(F, s3, a3, b3);

        // prefetch next pair: uniform 8 loads, in flight across the window
        if (k + 1 < CPB / 2) {
            const f32x4* fA = fe4base + (size_t)(2 * k + 2) * (NF / 4);
            const f32x4* fB = fA + (NF / 4);
            a0 = fA[tid]; a1 = fA[tid + 1024]; a2 = fA[tid + 2048]; a3 = fA[tl];
            b0 = fB[tid]; b1 = fB[tid + 1024]; b2 = fB[tid + 2048]; b3 = fB[tl];
        }

        LGKM_BAR();   // scatter(k) visible to all; gather(k-1) complete too

        // gather + store means for both channels of pair k
        float* oA = out + (bc0 + (size_t)(2 * k)) * NT;
        float* oB = out + (bc0 + (size_t)(2 * k + 1)) * NT;
#pragma unroll
        for (int it = 0; it < 7; ++it) GATHER_ST(F, pv[it], tid + it * 1024);
        if (t8) GATHER_ST(F, pv[7], 7168 + tid);
    }
#undef GATHER_ST
#undef PAIR_WRITE
}

// Fallback (round-2 path) if workspace is too small.
__device__ __forceinline__ void lds_fadd(unsigned addr, float v) {
    asm volatile("ds_add_f32 %0, %1" :: "v"(addr), "v"(v));
}
__global__ __launch_bounds__(256) void pool_fused_kernel(const float* __restrict__ fe,
                                                         const int* __restrict__ gid,
                                                         float* __restrict__ out) {
    __shared__ float acc[NT];
    __shared__ int cnt[NT];
    const int bc = blockIdx.x, b = bc >> 8, tid = threadIdx.x;
    for (int t = tid; t < NT; t += 256) { acc[t] = 0.0f; cnt[t] = 0; }
    __syncthreads();
    const unsigned accb = (unsigned)(uintptr_t)acc;
    const float4* fe4 = (const float4*)(fe + (size_t)bc * NF);
    const int4* gid4 = (const int4*)(gid + (size_t)b * NF);
    for (int i = tid; i < NF / 4; i += 256) {
        float4 v = fe4[i];
        int4 g = gid4[i];
        lds_fadd(accb + 4u * (unsigned)g.x, v.x); atomicAdd(&cnt[g.x], 1);
        lds_fadd(accb + 4u * (unsigned)g.y, v.y); atomicAdd(&cnt[g.y], 1);
        lds_fadd(accb + 4u * (unsigned)g.z, v.z); atomicAdd(&cnt[g.z], 1);
        lds_fadd(accb + 4u * (unsigned)g.w, v.w); atomicAdd(&cnt[g.w], 1);
    }
    asm volatile("s_waitcnt lgkmcnt(0)" ::: "memory");
    __syncthreads();
    float* orow = out + (size_t)bc * NT;
    for (int t = tid; t < NT; t += 256) {
        int n = cnt[t];
        orow[t] = acc[t] / (float)(n > 0 ? n : 1);
    }
}

extern "C" void kernel_launch(void* const* d_in, const int* in_sizes, int n_in,
                              void* d_out, int out_size, void* d_ws, size_t ws_size,
                              hipStream_t stream) {
    const float* fe = (const float*)d_in[0];
    const int* gid = (const int*)d_in[1];
    float* out = (float*)d_out;

    // workspace layout (bytes)
    const size_t O_CNT = 0;          // int [NB*NT]   512000
    const size_t O_CUR = 512000;     // u32 [NB*NT]   512000
    const size_t O_PK  = 1024000;    // u32 [NB*NT]   512000
    const size_t O_SP  = 1536000;    // u16 [NB*NF]   512000
    const size_t TOTAL = 2048000;

    if (ws_size >= TOTAL) {
        char* w = (char*)d_ws;
        int* cnt = (int*)(w + O_CNT);
        uint* cursor = (uint*)(w + O_CUR);
        uint* pk = (uint*)(w + O_PK);
        ushort* sp = (ushort*)(w + O_SP);

        static bool lds_opted = false;
        if (!lds_opted) {
            (void)hipFuncSetAttribute((const void*)pool_kernel,
                                      hipFuncAttributeMaxDynamicSharedMemorySize,
                                      128000);
            lds_opted = true;
        }

        (void)hipMemsetAsync(cnt, 0, 512000, stream);
        hist_kernel<<<(NB * NF / 4 + 255) / 256, 256, 0, stream>>>(gid, cnt);
        scan_kernel<<<NB, 256, 0, stream>>>(cnt, pk, cursor);
        invperm_kernel<<<NB * 16, 256, 0, stream>>>(gid, cursor, sp);
        pool_kernel<<<NB * (NC / CPB), 1024, 128000, stream>>>(fe, sp, pk, out);
    } else {
        pool_fused_kernel<<<NB * NC, 256, 0, stream>>>(fe, gid, out);
    }
}